// Round 12
// baseline (164.303 us; speedup 1.0000x reference)
//
#include <hip/hip_runtime.h>

// GIN: 2x GINConv(eps=0), N=50000, E=800000, d=128. bf16 + MFMA.
// R12: LPT load-balance for the gather. sort_kernel bin-packs the 64 nodes of
// each bucket into the 32 16-lane groups by degree (bitonic sort + greedy
// argmin), emitting perm[64]+gcut[33]. Conv gather walks its group's node
// list -> per-group edge counts equalized (was Poisson straggler ~1.45x with
// barrier-synced blocks). R9/R10/R11 concurrency levers all nulled; imbalance
// is the remaining structural candidate. Gather body = R8's 4-batch loop.
// ws: [ xb | zb | wt | gcnt | ebuf | sbuf | noff | ngcut | nperm ]

#define NN 50000
#define NE 800000
#define FD 128
#define BNODES 64
#define NB 782           // ceil(NN/64); bucket 781 has 16 nodes
#define BCAP 1536        // max edges/bucket: mean 1024, sigma 32 -> +16 sigma
#define EPW 4096
#define NWG_BIN 196      // ceil(NE/EPW)

typedef unsigned short u16;
typedef unsigned char u8;
typedef unsigned int u32;
typedef __attribute__((ext_vector_type(8))) short bf16x8;
typedef __attribute__((ext_vector_type(4))) float f32x4;

static __device__ __forceinline__ float b2f(u16 u) {
    return __uint_as_float(((u32)u) << 16);
}
static __device__ __forceinline__ u16 f2b(float f) {
    u32 x = __float_as_uint(f);
    u32 r = x + 0x7FFFu + ((x >> 16) & 1u);   // RNE
    return (u16)(r >> 16);
}

// unpack-accumulate a uint4 (8 bf16) into acc0/acc1 via exact float-bit tricks
#define ACCUM(v) do { \
    acc0.x += __uint_as_float((v).x << 16); \
    acc0.y += __uint_as_float((v).x & 0xFFFF0000u); \
    acc0.z += __uint_as_float((v).y << 16); \
    acc0.w += __uint_as_float((v).y & 0xFFFF0000u); \
    acc1.x += __uint_as_float((v).z << 16); \
    acc1.y += __uint_as_float((v).z & 0xFFFF0000u); \
    acc1.z += __uint_as_float((v).w << 16); \
    acc1.w += __uint_as_float((v).w & 0xFFFF0000u); } while (0)

// ---------------- converts ----------------

__global__ __launch_bounds__(256) void convert_x_kernel(
    const float* __restrict__ x, u16* __restrict__ xb)
{
    int gid = blockIdx.x * 256 + threadIdx.x;
    size_t base = (size_t)gid * 8;
    float4 a = *reinterpret_cast<const float4*>(x + base);
    float4 b = *reinterpret_cast<const float4*>(x + base + 4);
    u32 w0 = (u32)f2b(a.x) | ((u32)f2b(a.y) << 16);
    u32 w1 = (u32)f2b(a.z) | ((u32)f2b(a.w) << 16);
    u32 w2 = (u32)f2b(b.x) | ((u32)f2b(b.y) << 16);
    u32 w3 = (u32)f2b(b.z) | ((u32)f2b(b.w) << 16);
    uint4 o = {w0, w1, w2, w3};
    *reinterpret_cast<uint4*>(xb + base) = o;
}

// W [128][128] fp32 row-major -> WT[n][k] = W[k][n] bf16
__global__ __launch_bounds__(256) void convert_w_kernel(
    const float* __restrict__ w0, const float* __restrict__ w1,
    const float* __restrict__ w2, const float* __restrict__ w3,
    u16* __restrict__ wt)
{
    int b = blockIdx.x;
    const float* W = (b == 0) ? w0 : (b == 1) ? w1 : (b == 2) ? w2 : w3;
    u16* out = wt + (size_t)b * FD * FD;
    for (int idx = threadIdx.x; idx < FD * FD; idx += 256) {
        int n = idx >> 7, k = idx & 127;
        out[idx] = f2b(W[k * FD + n]);
    }
}

// ---------------- bucket binning (64-node buckets) ----------------

__global__ __launch_bounds__(256) void bin_kernel(
    const int* __restrict__ ei, u32* __restrict__ ebuf, int* __restrict__ gcnt)
{
    __shared__ int cnt[1024];
    __shared__ int lofs[1024];
    __shared__ int cur[1024];
    __shared__ int gb[1024];
    __shared__ int csum[16];
    __shared__ int cofs[16];
    __shared__ u32 vals[EPW];
    __shared__ u16 bkt[EPW];

    const int tid = threadIdx.x, lane = tid & 63, wv = tid >> 6;
    const int e0 = blockIdx.x * EPW;
    const int nE = min(EPW, NE - e0);
    const int* dstp = ei + NE;

    for (int i = tid; i < 1024; i += 256) { cnt[i] = 0; cur[i] = 0; }
    __syncthreads();

    for (int k = 0; k < EPW / 256; ++k) {
        int e = e0 + k * 256 + tid;
        if (e < NE) atomicAdd(&cnt[(u32)dstp[e] >> 6], 1);
    }
    __syncthreads();

    // exclusive scan over 1024 slots (16 chunks of 64)
    for (int cc = 0; cc < 4; ++cc) {
        int c = wv + cc * 4;
        int i = c * 64 + lane;
        int v = cnt[i];
        int sc = v;
#pragma unroll
        for (int s = 1; s < 64; s <<= 1) {
            int t = __shfl_up(sc, s);
            if (lane >= s) sc += t;
        }
        lofs[i] = sc - v;
        if (lane == 63) csum[c] = sc;
    }
    __syncthreads();
    if (wv == 0) {
        int s = (lane < 16) ? csum[lane] : 0;
        int sc = s;
#pragma unroll
        for (int st = 1; st < 16; st <<= 1) {
            int u = __shfl_up(sc, st);
            if (lane >= st) sc += u;
        }
        if (lane < 16) cofs[lane] = sc - s;
    }
    __syncthreads();
    for (int cc = 0; cc < 4; ++cc) {
        int c = wv + cc * 4;
        lofs[c * 64 + lane] += cofs[c];
    }
    __syncthreads();

    // place (bucket-grouped in LDS)
    for (int k = 0; k < EPW / 256; ++k) {
        int e = e0 + k * 256 + tid;
        if (e < NE) {
            int s = ei[e];
            u32 d = (u32)dstp[e];
            int b = d >> 6;
            int p = lofs[b] + atomicAdd(&cur[b], 1);
            vals[p] = (u32)s | ((d & 63u) << 16);
            bkt[p] = (u16)b;
        }
    }
    __syncthreads();

    // claim global chunks
    for (int b = tid; b < NB; b += 256) {
        int c = cur[b];
        gb[b] = c ? atomicAdd(&gcnt[b], c) : 0;
    }
    __syncthreads();

    // flush bucket-grouped -> contiguous runs
    for (int idx = tid; idx < nE; idx += 256) {
        int b = bkt[idx];
        ebuf[(size_t)b * BCAP + gb[b] + (idx - lofs[b])] = vals[idx];
    }
}

// ---------------- one-time counting sort per bucket + LPT group packing ----

__global__ __launch_bounds__(256) void sort_kernel(
    const u32* __restrict__ ebuf, const int* __restrict__ gcnt,
    u16* __restrict__ sbuf, int* __restrict__ noff,
    int* __restrict__ ngcut, u8* __restrict__ nperm)
{
    __shared__ u32 stage[BCAP];    // 6 KB
    __shared__ u16 sorted[BCAP];   // 3 KB
    __shared__ int cnt64[64];
    __shared__ int off64[65];
    __shared__ int cur64[64];
    __shared__ u8 ownerL[64];
    __shared__ u8 permL[64];
    __shared__ int g32[33];
    __shared__ int c32[32];

    const int tid = threadIdx.x, lane = tid & 63, wv = tid >> 6;
    const int b = blockIdx.x;
    const int cnt = gcnt[b];
    const u32* eb = ebuf + (size_t)b * BCAP;

    if (tid < 64) cnt64[tid] = 0;
    if (tid < 33) g32[tid] = 0;
    if (tid >= 64 && tid < 96) c32[tid - 64] = 0;
    __syncthreads();

    for (int e = tid; e < cnt; e += 256) {
        u32 v = eb[e];
        stage[e] = v;
        atomicAdd(&cnt64[v >> 16], 1);
    }
    __syncthreads();

    if (wv == 0) {
        int v = cnt64[lane];
        int sc = v;
#pragma unroll
        for (int s = 1; s < 64; s <<= 1) {
            int t = __shfl_up(sc, s);
            if (lane >= s) sc += t;
        }
        off64[lane + 1] = sc;
        cur64[lane] = sc - v;
        if (lane == 0) off64[0] = 0;
    }
    __syncthreads();

    for (int e = tid; e < cnt; e += 256) {
        u32 v = stage[e];
        int pos = atomicAdd(&cur64[v >> 16], 1);
        sorted[pos] = (u16)(v & 0xFFFFu);   // src < 50000 fits u16
    }
    __syncthreads();

    // ---- LPT: pack 64 nodes into 32 groups, balanced by degree ----
    if (wv == 0) {
        int deg = cnt64[lane];
        int key = (deg << 6) | lane;        // unique keys
        // bitonic ascending sort across 64 lanes
#pragma unroll
        for (int k = 2; k <= 64; k <<= 1) {
#pragma unroll
            for (int j = k >> 1; j > 0; j >>= 1) {
                int partner = __shfl_xor(key, j);
                bool up = (lane & k) == 0;
                bool upper = (lane & j) != 0;
                int lo = min(key, partner), hi = max(key, partner);
                key = up ? (upper ? hi : lo) : (upper ? lo : hi);
            }
        }
        // greedy: largest degree first into least-loaded group
        int myload = (lane < 32) ? 0 : 0x7FFFFFFF;
        for (int i = 63; i >= 0; --i) {
            int ki = __shfl(key, i);
            int d = ki >> 6, n = ki & 63;
            int bv = myload, bl = lane;
#pragma unroll
            for (int s = 1; s < 32; s <<= 1) {
                int ov = __shfl_xor(bv, s);
                int ol = __shfl_xor(bl, s);
                if (ov < bv || (ov == bv && ol < bl)) { bv = ov; bl = ol; }
            }
            if (lane == bl) myload += d;
            if (lane == 0) ownerL[n] = (u8)bl;
        }
    }
    __syncthreads();
    if (tid < 64) atomicAdd(&g32[ownerL[tid] + 1], 1);
    __syncthreads();
    if (tid == 0)
        for (int i = 1; i <= 32; ++i) g32[i] += g32[i - 1];   // g32 = gcut
    __syncthreads();
    if (tid < 64) {
        int ow = ownerL[tid];
        int p = g32[ow] + atomicAdd(&c32[ow], 1);
        permL[p] = (u8)tid;
    }
    __syncthreads();

    // ---- write out ----
    if (tid < 65) noff[b * 65 + tid] = off64[tid];
    if (tid < 33) ngcut[b * 33 + tid] = g32[tid];
    if (tid >= 64 && tid < 80)
        reinterpret_cast<u32*>(nperm + (size_t)b * 64)[tid - 64] =
            reinterpret_cast<const u32*>(permL)[tid - 64];
    u32* sb = (u32*)(sbuf + (size_t)b * BCAP);
    const u32* so = (const u32*)sorted;
    for (int i = tid; i * 2 < cnt; i += 256) sb[i] = so[i];
}

// ---------------- fused conv (R8 structure + LPT-balanced gather) ----------
// Block = bucket = M-tile (64 nodes). 8 waves x 4 groups = 32 groups; group
// gi processes nodes perm[gcut[gi]..gcut[gi+1]) (degree-balanced). Gather:
// dwordx4 row reads, 4-deep register batches, float-bit unpack.
// GEMM: 8 waves as 2Mx4N; weights read as B-frags from global (L2-resident).
// k-map phi(g,i)=8g+i both operands; D: col=lane&15, row=(lane>>4)*4+reg.

template <bool F32OUT>
__global__ __launch_bounds__(512, 6) void conv_kernel(
    const u16* __restrict__ h, const u16* __restrict__ sbuf,
    const int* __restrict__ noff, const int* __restrict__ ngcut,
    const u8* __restrict__ nperm,
    const u16* __restrict__ WTa, const float* __restrict__ biasa,
    const u16* __restrict__ WTb, const float* __restrict__ biasb,
    void* __restrict__ outv)
{
    __shared__ u16 a_lds[64][136];   // 17.4 KB
    __shared__ u16 t_lds[64][136];   // 17.4 KB
    __shared__ u16 sorted[BCAP];     // 3 KB
    __shared__ int off[65];
    __shared__ int gcut[33];
    __shared__ u8 perm[64];

    const int tid = threadIdx.x;
    const int lane = tid & 63;
    const int wv = tid >> 6;         // 0..7
    const int b = blockIdx.x;
    const int node0 = b * BNODES;
    const int nNodes = min(BNODES, NN - node0);
    const int g = lane >> 4;         // group-in-wave 0..3
    const int l16 = lane & 15;
    const int gi = wv * 4 + g;       // 0..31

    // ---- phase 1: edge list + offsets + group assignment ----
    if (tid < 65) off[tid] = noff[b * 65 + tid];
    if (tid >= 96 && tid < 129) gcut[tid - 96] = ngcut[b * 33 + (tid - 96)];
    if (tid >= 160 && tid < 176)
        reinterpret_cast<u32*>(perm)[tid - 160] =
            reinterpret_cast<const u32*>(nperm + (size_t)b * 64)[tid - 160];
    __syncthreads();
    const int cnt = off[64];
    {
        const u32* sb = (const u32*)(sbuf + (size_t)b * BCAP);
        u32* so = (u32*)sorted;
        for (int i = tid; i * 2 < cnt; i += 512) so[i] = sb[i];
    }
    __syncthreads();

    // ---- phase 2: gather into a_lds (group gi's node list, LPT-balanced) ----
    const u16* hcol = h + l16 * 8;   // this lane's 8-feature slice

    for (int j = gcut[gi]; j < gcut[gi + 1]; ++j) {
        const int n = perm[j];
        float4 acc0 = {0.f, 0.f, 0.f, 0.f};
        float4 acc1 = {0.f, 0.f, 0.f, 0.f};
        if (n < nNodes) {
            uint4 v = *reinterpret_cast<const uint4*>(hcol + (size_t)(node0 + n) * FD);
            ACCUM(v);   // self term
            const int end = off[n + 1];
            const int endm1 = end - 1;
            for (int e = off[n]; e < end; e += 4) {
                const int m = end - e;
                uint4 vv[4];
#pragma unroll
                for (int k = 0; k < 4; ++k) {
                    int ee = e + k; if (ee > endm1) ee = endm1;  // dup tail: L1-hit
                    vv[k] = *reinterpret_cast<const uint4*>(
                        hcol + (size_t)sorted[ee] * FD);
                }
                ACCUM(vv[0]);
                if (m > 1) ACCUM(vv[1]);
                if (m > 2) ACCUM(vv[2]);
                if (m > 3) ACCUM(vv[3]);
            }
        }
        uint4 o;
        o.x = (u32)f2b(acc0.x) | ((u32)f2b(acc0.y) << 16);
        o.y = (u32)f2b(acc0.z) | ((u32)f2b(acc0.w) << 16);
        o.z = (u32)f2b(acc1.x) | ((u32)f2b(acc1.y) << 16);
        o.w = (u32)f2b(acc1.z) | ((u32)f2b(acc1.w) << 16);
        *reinterpret_cast<uint4*>(&a_lds[n][l16 * 8]) = o;   // zeros for pad rows
    }
    __syncthreads();

    const int mbase = (wv >> 2) * 32;   // 0 or 32
    const int nbase = (wv & 3) * 32;    // 0,32,64,96

    // ---- phase 3: t = relu(a @ Wa + ba) ----
    f32x4 acc[2][2];
#pragma unroll
    for (int m = 0; m < 2; ++m)
#pragma unroll
        for (int nf = 0; nf < 2; ++nf) acc[m][nf] = (f32x4){0.f, 0.f, 0.f, 0.f};

#pragma unroll
    for (int k0 = 0; k0 < 4; ++k0) {
        const int kk = k0 * 32 + g * 8;
        bf16x8 a0 = *reinterpret_cast<const bf16x8*>(&a_lds[mbase + l16][kk]);
        bf16x8 a1 = *reinterpret_cast<const bf16x8*>(&a_lds[mbase + 16 + l16][kk]);
#pragma unroll
        for (int nf = 0; nf < 2; ++nf) {
            bf16x8 bb = *reinterpret_cast<const bf16x8*>(
                WTa + (size_t)(nbase + nf * 16 + l16) * FD + kk);
            acc[0][nf] = __builtin_amdgcn_mfma_f32_16x16x32_bf16(a0, bb, acc[0][nf], 0, 0, 0);
            acc[1][nf] = __builtin_amdgcn_mfma_f32_16x16x32_bf16(a1, bb, acc[1][nf], 0, 0, 0);
        }
    }

#pragma unroll
    for (int m = 0; m < 2; ++m) {
#pragma unroll
        for (int nf = 0; nf < 2; ++nf) {
            int col = nbase + nf * 16 + l16;
            float bc = biasa[col];
#pragma unroll
            for (int r = 0; r < 4; ++r) {
                int row = mbase + 16 * m + g * 4 + r;
                t_lds[row][col] = f2b(fmaxf(acc[m][nf][r] + bc, 0.f));
            }
        }
    }
    __syncthreads();

    // ---- phase 4: out = relu(t @ Wb + bb) ----
    f32x4 acc2[2][2];
#pragma unroll
    for (int m = 0; m < 2; ++m)
#pragma unroll
        for (int nf = 0; nf < 2; ++nf) acc2[m][nf] = (f32x4){0.f, 0.f, 0.f, 0.f};

#pragma unroll
    for (int k0 = 0; k0 < 4; ++k0) {
        const int kk = k0 * 32 + g * 8;
        bf16x8 a0 = *reinterpret_cast<const bf16x8*>(&t_lds[mbase + l16][kk]);
        bf16x8 a1 = *reinterpret_cast<const bf16x8*>(&t_lds[mbase + 16 + l16][kk]);
#pragma unroll
        for (int nf = 0; nf < 2; ++nf) {
            bf16x8 bb = *reinterpret_cast<const bf16x8*>(
                WTb + (size_t)(nbase + nf * 16 + l16) * FD + kk);
            acc2[0][nf] = __builtin_amdgcn_mfma_f32_16x16x32_bf16(a0, bb, acc2[0][nf], 0, 0, 0);
            acc2[1][nf] = __builtin_amdgcn_mfma_f32_16x16x32_bf16(a1, bb, acc2[1][nf], 0, 0, 0);
        }
    }

    if (F32OUT) {
        // f32 frag stores are already full-line (16 consecutive f32 = 64B)
#pragma unroll
        for (int m = 0; m < 2; ++m) {
#pragma unroll
            for (int nf = 0; nf < 2; ++nf) {
                int col = nbase + nf * 16 + l16;
                float bc = biasb[col];
#pragma unroll
                for (int r = 0; r < 4; ++r) {
                    int row = node0 + mbase + 16 * m + g * 4 + r;
                    if (row < NN) {
                        float v = fmaxf(acc2[m][nf][r] + bc, 0.f);
                        reinterpret_cast<float*>(outv)[(size_t)row * FD + col] = v;
                    }
                }
            }
        }
    } else {
        // stage bf16 result in t_lds (free after phase 4 reads), then
        // coalesced 16B/lane copy-out — avoids 2x partial-line writebacks.
        __syncthreads();
#pragma unroll
        for (int m = 0; m < 2; ++m) {
#pragma unroll
            for (int nf = 0; nf < 2; ++nf) {
                int col = nbase + nf * 16 + l16;
                float bc = biasb[col];
#pragma unroll
                for (int r = 0; r < 4; ++r) {
                    int row = mbase + 16 * m + g * 4 + r;
                    t_lds[row][col] = f2b(fmaxf(acc2[m][nf][r] + bc, 0.f));
                }
            }
        }
        __syncthreads();
        u16* outp = reinterpret_cast<u16*>(outv);
#pragma unroll
        for (int it = 0; it < 2; ++it) {
            int idx = tid + it * 512;
            int r = idx >> 4, c = (idx & 15) * 8;
            if (node0 + r < NN)
                *reinterpret_cast<uint4*>(outp + (size_t)(node0 + r) * FD + c) =
                    *reinterpret_cast<const uint4*>(&t_lds[r][c]);
        }
    }
}

extern "C" void kernel_launch(void* const* d_in, const int* in_sizes, int n_in,
                              void* d_out, int out_size, void* d_ws, size_t ws_size,
                              hipStream_t stream) {
    const float* x   = (const float*)d_in[0];
    const int*   ei  = (const int*)d_in[1];
    const float* W1a = (const float*)d_in[2];
    const float* b1a = (const float*)d_in[3];
    const float* W1b = (const float*)d_in[4];
    const float* b1b = (const float*)d_in[5];
    const float* W2a = (const float*)d_in[6];
    const float* b2a = (const float*)d_in[7];
    const float* W2b = (const float*)d_in[8];
    const float* b2b = (const float*)d_in[9];

    const size_t feat = (size_t)NN * FD;
    u16* xb = (u16*)d_ws;             // 12.8 MB (x bf16)
    u16* zb = xb + feat;              // 12.8 MB (h1 bf16)
    u16* wt = zb + feat;              // 128 KB
    int* gcnt = (int*)(wt + 4 * FD * FD);         // 1024 ints
    u32* ebuf = (u32*)(gcnt + 1024);              // NB*BCAP*4 = 4.80 MB
    u16* sbuf = (u16*)(ebuf + (size_t)NB * BCAP); // NB*BCAP*2 = 2.40 MB
    int* noff = (int*)(sbuf + (size_t)NB * BCAP); // NB*65*4 = 204 KB
    int* ngcut = noff + NB * 65;                  // NB*33*4 = 103 KB
    u8*  nperm = (u8*)(ngcut + NB * 33);          // NB*64   = 50 KB

    const int cBlocks = (int)(feat / (256 * 8));  // 3125

    convert_x_kernel<<<cBlocks, 256, 0, stream>>>(x, xb);
    convert_w_kernel<<<4, 256, 0, stream>>>(W1a, W1b, W2a, W2b, wt);

    hipMemsetAsync(gcnt, 0, NB * sizeof(int), stream);
    bin_kernel<<<NWG_BIN, 256, 0, stream>>>(ei, ebuf, gcnt);
    sort_kernel<<<NB, 256, 0, stream>>>(ebuf, gcnt, sbuf, noff, ngcut, nperm);

    // conv1: xb -> zb (bf16)
    conv_kernel<false><<<NB, 512, 0, stream>>>(
        xb, sbuf, noff, ngcut, nperm, wt, b1a, wt + 1 * FD * FD, b1b, zb);
    // conv2: zb -> d_out (fp32)
    conv_kernel<true><<<NB, 512, 0, stream>>>(
        zb, sbuf, noff, ngcut, nperm, wt + 2 * FD * FD, b2a, wt + 3 * FD * FD, b2b, (float*)d_out);
}